// Round 2
// baseline (447.044 us; speedup 1.0000x reference)
//
#include <hip/hip_runtime.h>
#include <hip/hip_bf16.h>
#include <cmath>

// Problem constants: B=2, C=128, H=W=160, K=3, K2=9, G=8, Cg=16.
constexpr int Bc = 2;
constexpr int Cch = 128;
constexpr int Hc = 160;
constexpr int Wc = 160;
constexpr int HWc = Hc * Wc;          // 25600
constexpr int NPIX = Bc * HWc;        // 51200

// ---------------------------------------------------------------------------
// Weight prep: pack w_off (18 oc) + w_dyn (72 oc) into wT[c][kx][oc'] with
// padded strides: wT[c*288 + kx*96 + oc], oc in [0,90): 0..17 offset conv,
// 18..89 dyn conv. Works for both 1x3 and 3x1 (taps contiguous either way).
// ---------------------------------------------------------------------------
__global__ void wprep_k(const float* __restrict__ woff,
                        const float* __restrict__ wdyn,
                        float* __restrict__ wT) {
    int idx = blockIdx.x * 256 + threadIdx.x;      // 34560 = 128*3*90 total
    int oc = idx % 90;
    int t = idx / 90;
    int kx = t % 3;
    int c = t / 3;
    float v = (oc < 18) ? woff[(oc * Cch + c) * 3 + kx]
                        : wdyn[((oc - 18) * Cch + c) * 3 + kx];
    wT[c * 288 + kx * 96 + oc] = v;
}

// ---------------------------------------------------------------------------
// Generic 32x32 tiled transpose (per batch): in [R][Cn] -> out [Cn][R].
// ---------------------------------------------------------------------------
__global__ void transpose_k(const float* __restrict__ in, float* __restrict__ out,
                            int R, int Cn) {
    __shared__ float tile[32][33];
    int b = blockIdx.z;
    const float* inb = in + (size_t)b * R * Cn;
    float* outb = out + (size_t)b * R * Cn;
    int j0 = blockIdx.x * 32;   // col tile of input
    int i0 = blockIdx.y * 32;   // row tile of input
    for (int di = threadIdx.y; di < 32; di += 8) {
        int i = i0 + di, j = j0 + threadIdx.x;
        if (i < R && j < Cn) tile[di][threadIdx.x] = inb[(size_t)i * Cn + j];
    }
    __syncthreads();
    for (int dj = threadIdx.y; dj < 32; dj += 8) {
        int j = j0 + dj, i = i0 + threadIdx.x;
        if (j < Cn && i < R) outb[(size_t)j * R + i] = tile[threadIdx.x][dj];
    }
}

// ---------------------------------------------------------------------------
// Fused conv, both directions in one launch.
// grid = (800 pixel-blocks, 2 oc-halves, 2 directions), block = 64 (1 wave).
// Thread = one output pixel, 45 fp32 accumulators (one oc-half).
// x read NCHW (lane==w -> coalesced); weights wave-uniform (scalar loads).
// Explicit c+1 prefetch hides load latency behind the 135-FMA block.
// z==0: horizontal 1x3 pad (0,1);  z==1: vertical 3x1 pad (1,0).
// ---------------------------------------------------------------------------
__global__ __launch_bounds__(64) void conv_k(
        const float* __restrict__ x,
        const float* __restrict__ wTh, const float* __restrict__ wTv,
        const float* __restrict__ b_hoff, const float* __restrict__ b_hw,
        const float* __restrict__ b_voff, const float* __restrict__ b_vw,
        float* __restrict__ offh, float* __restrict__ dynh,
        float* __restrict__ offv, float* __restrict__ dynv) {
    int pix = blockIdx.x * 64 + threadIdx.x;       // 800*64 = 51200 exact
    int half = blockIdx.y;
    bool horiz = (blockIdx.z == 0);
    int b = pix / HWc;
    int hw = pix - b * HWc;
    int h = hw / Wc;
    int w = hw - h * Wc;

    const float* wT   = horiz ? wTh  : wTv;
    const float* boff = horiz ? b_hoff : b_voff;
    const float* bdyn = horiz ? b_hw  : b_vw;
    float* offo = horiz ? offh : offv;
    float* dyno = horiz ? dynh : dynv;
    const int step = horiz ? 1 : Wc;
    const bool v0 = horiz ? (w > 0) : (h > 0);
    const bool v2 = horiz ? (w < Wc - 1) : (h < Hc - 1);

    float acc[45];
    if (half == 0) {
#pragma unroll
        for (int i = 0; i < 18; ++i) acc[i] = boff[i];
#pragma unroll
        for (int i = 0; i < 27; ++i) acc[18 + i] = bdyn[i];
    } else {
#pragma unroll
        for (int i = 0; i < 45; ++i) acc[i] = bdyn[27 + i];
    }

    const float* xb = x + b * Cch * HWc + hw;
    const float* wc = wT + half * 45;

    // preload c = 0
    float xm = v0 ? xb[-step] : 0.f;
    float xv = xb[0];
    float xp = v2 ? xb[step] : 0.f;

#pragma unroll 1
    for (int c = 0; c < Cch; ++c) {
        // prefetch c+1 (clamped re-read of c=127 on last iter: branchless)
        const float* xn = xb + (c < Cch - 1 ? c + 1 : Cch - 1) * HWc;
        float nm = v0 ? xn[-step] : 0.f;
        float nv = xn[0];
        float np = v2 ? xn[step] : 0.f;
#pragma unroll
        for (int oc = 0; oc < 45; ++oc) {
            float a = acc[oc];
            a = fmaf(wc[oc], xm, a);
            a = fmaf(wc[96 + oc], xv, a);
            a = fmaf(wc[192 + oc], xp, a);
            acc[oc] = a;
        }
        wc += 288;
        xm = nm; xv = nv; xp = np;
    }

    if (half == 0) {
        float* ob = offo + b * 18 * HWc + hw;
#pragma unroll
        for (int i = 0; i < 18; ++i) ob[i * HWc] = acc[i];
        float* db = dyno + b * 72 * HWc + hw;
#pragma unroll
        for (int i = 0; i < 27; ++i) db[i * HWc] = acc[18 + i];
    } else {
        float* db = dyno + b * 72 * HWc + 27 * HWc + hw;
#pragma unroll
        for (int i = 0; i < 45; ++i) db[i * HWc] = acc[i];
    }
}

// ---------------------------------------------------------------------------
// Deformable aggregation. One wave per output pixel; lane holds channels
// (2*lane, 2*lane+1). xT/outT are NHWC so each bilinear tap is one coalesced
// float2 load per lane (512B per wave). off: [B,18,H,W] (0..8 dy, 9..17 dx),
// dynw: [B,72,H,W] (channel = g*9+k), planar -> wave-broadcast reads.
// ---------------------------------------------------------------------------
__global__ __launch_bounds__(256) void deform_k(const float* __restrict__ xT,
                                                const float* __restrict__ off,
                                                const float* __restrict__ dynw,
                                                float* __restrict__ outT) {
    int lane = threadIdx.x & 63;
    int pix = blockIdx.x * 4 + (threadIdx.x >> 6);   // 12800*4 = 51200 exact
    int b = pix / HWc;
    int hw = pix - b * HWc;
    int h = hw / Wc;
    int w = hw - h * Wc;
    int c0 = lane * 2;
    int g = lane >> 3;                                // = (2*lane)/16

    const float* offb = off + b * 18 * HWc + hw;
    const float* dynb = dynw + b * 72 * HWc + g * 9 * HWc + hw;
    const float* xb = xT + (size_t)b * HWc * Cch;

    float acc0 = 0.f, acc1 = 0.f;
#pragma unroll
    for (int k = 0; k < 9; ++k) {
        float dy = offb[k * HWc];
        float dx = offb[(9 + k) * HWc];
        float wt = dynb[k * HWc];
        float py = (float)(h - 1 + k / 3) + dy;
        float px = (float)(w - 1 + k % 3) + dx;
        float y0f = floorf(py), x0f = floorf(px);
        float fy = py - y0f, fx = px - x0f;
        int y0 = (int)y0f, x0 = (int)x0f;
        int y1 = y0 + 1, x1 = x0 + 1;
        float w00 = (1.f - fy) * (1.f - fx) * wt;
        float w01 = (1.f - fy) * fx * wt;
        float w10 = fy * (1.f - fx) * wt;
        float w11 = fy * fx * wt;

        {
            bool v = (y0 >= 0) & (y0 < Hc) & (x0 >= 0) & (x0 < Wc);
            int yc = min(max(y0, 0), Hc - 1), xc = min(max(x0, 0), Wc - 1);
            float2 t = *reinterpret_cast<const float2*>(&xb[((size_t)yc * Wc + xc) * Cch + c0]);
            float m = v ? w00 : 0.f;
            acc0 = fmaf(m, t.x, acc0);
            acc1 = fmaf(m, t.y, acc1);
        }
        {
            bool v = (y0 >= 0) & (y0 < Hc) & (x1 >= 0) & (x1 < Wc);
            int yc = min(max(y0, 0), Hc - 1), xc = min(max(x1, 0), Wc - 1);
            float2 t = *reinterpret_cast<const float2*>(&xb[((size_t)yc * Wc + xc) * Cch + c0]);
            float m = v ? w01 : 0.f;
            acc0 = fmaf(m, t.x, acc0);
            acc1 = fmaf(m, t.y, acc1);
        }
        {
            bool v = (y1 >= 0) & (y1 < Hc) & (x0 >= 0) & (x0 < Wc);
            int yc = min(max(y1, 0), Hc - 1), xc = min(max(x0, 0), Wc - 1);
            float2 t = *reinterpret_cast<const float2*>(&xb[((size_t)yc * Wc + xc) * Cch + c0]);
            float m = v ? w10 : 0.f;
            acc0 = fmaf(m, t.x, acc0);
            acc1 = fmaf(m, t.y, acc1);
        }
        {
            bool v = (y1 >= 0) & (y1 < Hc) & (x1 >= 0) & (x1 < Wc);
            int yc = min(max(y1, 0), Hc - 1), xc = min(max(x1, 0), Wc - 1);
            float2 t = *reinterpret_cast<const float2*>(&xb[((size_t)yc * Wc + xc) * Cch + c0]);
            float m = v ? w11 : 0.f;
            acc0 = fmaf(m, t.x, acc0);
            acc1 = fmaf(m, t.y, acc1);
        }
    }
    *reinterpret_cast<float2*>(&outT[(size_t)pix * Cch + c0]) = make_float2(acc0, acc1);
}

// ---------------------------------------------------------------------------
// Launch
// ---------------------------------------------------------------------------
extern "C" void kernel_launch(void* const* d_in, const int* in_sizes, int n_in,
                              void* d_out, int out_size, void* d_ws, size_t ws_size,
                              hipStream_t stream) {
    const float* x      = (const float*)d_in[0];
    const float* w_hoff = (const float*)d_in[1];
    const float* b_hoff = (const float*)d_in[2];
    const float* w_hw   = (const float*)d_in[3];
    const float* b_hw   = (const float*)d_in[4];
    const float* w_voff = (const float*)d_in[5];
    const float* b_voff = (const float*)d_in[6];
    const float* w_vw   = (const float*)d_in[7];
    const float* b_vw   = (const float*)d_in[8];
    float* out = (float*)d_out;
    float* ws = (float*)d_ws;

    // Workspace layout (floats), ~22.4M floats (~90 MB).
    float* wTh  = ws;                       // 36864
    float* wTv  = wTh + 36864;              // 36864
    float* xT   = wTv + 36864;              // 6,553,600  (NHWC x; later reused as NHWC out_v)
    float* offh = xT + 6553600;             // 921,600
    float* dynh = offh + 921600;            // 3,686,400
    float* offv = dynh + 3686400;           // 921,600
    float* dynv = offv + 921600;            // 3,686,400
    float* outh = dynv + 3686400;           // 6,553,600  (NHWC out_h)
    float* outv = xT;                       // alias: xT dead after deform pass 1

    // Weight packing (tiny)
    hipLaunchKernelGGL(wprep_k, dim3(135), dim3(256), 0, stream, w_hoff, w_hw, wTh);
    hipLaunchKernelGGL(wprep_k, dim3(135), dim3(256), 0, stream, w_voff, w_vw, wTv);

    // x NCHW -> NHWC (per batch: [128][25600] -> [25600][128])
    hipLaunchKernelGGL(transpose_k, dim3(800, 4, 2), dim3(32, 8), 0, stream,
                       x, xT, 128, 25600);

    // Fused offset/dyn-weight convs, both directions (reads original x, NCHW)
    hipLaunchKernelGGL(conv_k, dim3(800, 2, 2), dim3(64), 0, stream,
                       x, wTh, wTv, b_hoff, b_hw, b_voff, b_vw,
                       offh, dynh, offv, dynv);

    // Deformable aggregation passes
    hipLaunchKernelGGL(deform_k, dim3(12800), dim3(256), 0, stream,
                       xT, offh, dynh, outh);
    hipLaunchKernelGGL(deform_k, dim3(12800), dim3(256), 0, stream,
                       outh, offv, dynv, outv);

    // out_v NHWC -> NCHW into d_out (per batch: [25600][128] -> [128][25600])
    hipLaunchKernelGGL(transpose_k, dim3(4, 800, 2), dim3(32, 8), 0, stream,
                       outv, out, 25600, 128);
}

// Round 3
// 391.998 us; speedup vs baseline: 1.1404x; 1.1404x over previous
//
#include <hip/hip_runtime.h>
#include <hip/hip_bf16.h>
#include <cmath>

// Problem constants: B=2, C=128, H=W=160, K=3, K2=9, G=8, Cg=16.
constexpr int Cch = 128;
constexpr int Hc = 160;
constexpr int Wc = 160;
constexpr int HWc = Hc * Wc;          // 25600
constexpr int NPIX = 2 * HWc;         // 51200

typedef __attribute__((ext_vector_type(8))) short bf16x8;   // 8 bf16 = 4 VGPRs
typedef __attribute__((ext_vector_type(4))) float f32x4;

static __device__ __forceinline__ short f2bf(float v) {
    __hip_bfloat16 h = __float2bfloat16(v);
    return *reinterpret_cast<short*>(&h);
}
static __device__ __forceinline__ float bf2f(short s) {
    __hip_bfloat16 h = *reinterpret_cast<__hip_bfloat16*>(&s);
    return __bfloat162float(h);
}

// ---------------------------------------------------------------------------
// Weight prep: pack both directions' conv weights (18 offset oc + 72 dyn oc,
// padded to 96) into k-major bf16 hi/lo: w[dir][oc][tap][c], plus bias[dir][96].
// Layout index = ((dir*96 + oc)*3 + tap)*128 + c.
// ---------------------------------------------------------------------------
__global__ void wprep2_k(const float* __restrict__ wh_off, const float* __restrict__ wh_dyn,
                         const float* __restrict__ wv_off, const float* __restrict__ wv_dyn,
                         const float* __restrict__ bh_off, const float* __restrict__ bh_dyn,
                         const float* __restrict__ bv_off, const float* __restrict__ bv_dyn,
                         short* __restrict__ whi, short* __restrict__ wlo,
                         float* __restrict__ bias) {
    int idx = blockIdx.x * 256 + threadIdx.x;      // 73728 = 2*96*3*128 exact
    int c = idx & 127;
    int t = idx >> 7;
    int tap = t % 3;
    int oc = (t / 3) % 96;
    int dir = t / 288;
    const float* woff = dir ? wv_off : wh_off;
    const float* wdyn = dir ? wv_dyn : wh_dyn;
    float v = 0.f;
    if (oc < 18) v = woff[(oc * Cch + c) * 3 + tap];
    else if (oc < 90) v = wdyn[((oc - 18) * Cch + c) * 3 + tap];
    short hi = f2bf(v);
    whi[idx] = hi;
    wlo[idx] = f2bf(v - bf2f(hi));
    if (idx < 192) {
        int d2 = idx / 96, j = idx % 96;
        const float* boff = d2 ? bv_off : bh_off;
        const float* bdyn = d2 ? bv_dyn : bh_dyn;
        bias[idx] = j < 18 ? boff[j] : (j < 90 ? bdyn[j - 18] : 0.f);
    }
}

// ---------------------------------------------------------------------------
// x NCHW -> NHWC, emitting fp32 (for deform gather) + bf16 hi + bf16 lo
// (for the MFMA conv). 32x32 LDS tile per block.
// ---------------------------------------------------------------------------
__global__ void pack_k(const float* __restrict__ x, float* __restrict__ xT,
                       short* __restrict__ xh, short* __restrict__ xl) {
    __shared__ float tile[32][33];
    int b = blockIdx.z;
    int j0 = blockIdx.x * 32;          // hw
    int i0 = blockIdx.y * 32;          // c
    const float* inb = x + (size_t)b * Cch * HWc;
    for (int di = threadIdx.y; di < 32; di += 8)
        tile[di][threadIdx.x] = inb[(size_t)(i0 + di) * HWc + j0 + threadIdx.x];
    __syncthreads();
    size_t obase = (size_t)b * HWc * Cch;
    for (int dj = threadIdx.y; dj < 32; dj += 8) {
        int hw = j0 + dj, c = i0 + threadIdx.x;
        float v = tile[threadIdx.x][dj];
        size_t o = obase + (size_t)hw * Cch + c;
        xT[o] = v;
        short hi = f2bf(v);
        xh[o] = hi;
        xl[o] = f2bf(v - bf2f(hi));
    }
}

// ---------------------------------------------------------------------------
// MFMA conv: out[px][oc=96] = sum_{tap,c} w[oc][tap][c] * x[px_shift(tap)][c]
// per direction. M=pixels, N=96 oc, K=384, 3-chain bf16 precision split:
// (wh,xh) + (wh,xl) + (wl,xh). A-frags straight from NHWC bf16 global (8
// contiguous c per lane); B-frags from k-major packed weights (L1/L2-hot).
// Block = 4 waves; wave computes 16 px x 96 oc. grid=(800 px-tiles, 2 dirs).
// Output layout pixel-major: conv[px][96]: 0..8 dy, 9..17 dx, 18..89 dynw.
// ---------------------------------------------------------------------------
__global__ __launch_bounds__(256) void conv_mfma_k(
        const short* __restrict__ xh, const short* __restrict__ xl,
        const short* __restrict__ whi, const short* __restrict__ wlo,
        const float* __restrict__ bias,
        float* __restrict__ convH, float* __restrict__ convV) {
    int dir = blockIdx.y;
    int lane = threadIdx.x & 63;
    int wid = threadIdx.x >> 6;
    int px0 = blockIdx.x * 64 + wid * 16;
    int l15 = lane & 15;
    int kgrp = lane >> 4;

    // A-side pixel for this lane (m = l15)
    int px = px0 + l15;
    int bb = px >= HWc;
    int hw = px - bb * HWc;
    int h = hw / Wc, w = hw - h * Wc;

    const short* wsrc_h = whi + dir * 36864 + (size_t)l15 * 384 + kgrp * 8;
    const short* wsrc_l = wlo + dir * 36864 + (size_t)l15 * 384 + kgrp * 8;

    f32x4 acc[6];
#pragma unroll
    for (int i = 0; i < 6; ++i) acc[i] = f32x4{0.f, 0.f, 0.f, 0.f};

#pragma unroll
    for (int tap = 0; tap < 3; ++tap) {
        int vcoord, shw;
        if (dir == 0) { vcoord = w + tap - 1; shw = hw + (tap - 1); }
        else          { vcoord = h + tap - 1; shw = hw + (tap - 1) * Wc; }
        bool valid = (unsigned)vcoord < 160u;
        int shwc = min(max(shw, 0), HWc - 1);
        const short* aph = xh + ((size_t)(bb * HWc + shwc)) * Cch + kgrp * 8;
        const short* apl = xl + ((size_t)(bb * HWc + shwc)) * Cch + kgrp * 8;
#pragma unroll
        for (int ks = 0; ks < 4; ++ks) {
            bf16x8 ah = *reinterpret_cast<const bf16x8*>(aph + ks * 32);
            bf16x8 al = *reinterpret_cast<const bf16x8*>(apl + ks * 32);
            if (!valid) { ah = bf16x8{}; al = bf16x8{}; }
            const short* wph = wsrc_h + tap * 128 + ks * 32;
            const short* wpl = wsrc_l + tap * 128 + ks * 32;
#pragma unroll
            for (int nt = 0; nt < 6; ++nt) {
                bf16x8 bh = *reinterpret_cast<const bf16x8*>(wph + nt * 6144);
                bf16x8 bl = *reinterpret_cast<const bf16x8*>(wpl + nt * 6144);
                acc[nt] = __builtin_amdgcn_mfma_f32_16x16x32_bf16(ah, bh, acc[nt], 0, 0, 0);
                acc[nt] = __builtin_amdgcn_mfma_f32_16x16x32_bf16(al, bh, acc[nt], 0, 0, 0);
                acc[nt] = __builtin_amdgcn_mfma_f32_16x16x32_bf16(ah, bl, acc[nt], 0, 0, 0);
            }
        }
    }

    // Epilogue: D row = 4*kgrp + reg (= local px), col = l15 (+16*nt) = oc.
    float* outp = dir ? convV : convH;
    const float* bp = bias + dir * 96;
#pragma unroll
    for (int nt = 0; nt < 6; ++nt) {
        float bv = bp[nt * 16 + l15];
#pragma unroll
        for (int r = 0; r < 4; ++r) {
            int prow = px0 + kgrp * 4 + r;
            outp[(size_t)prow * 96 + nt * 16 + l15] = acc[nt][r] + bv;
        }
    }
}

// ---------------------------------------------------------------------------
// Deformable aggregation. One wave per output pixel; lane holds channels
// (2*lane, 2*lane+1). Gather src NHWC fp32 (coalesced float2 per tap).
// cv = pixel-major conv output [px][96]: dy=cv[k], dx=cv[9+k],
// wt=cv[18+g*9+k] -- all same cacheline region per pixel.
// ---------------------------------------------------------------------------
__global__ __launch_bounds__(256) void deform_k(const float* __restrict__ xT,
                                                const float* __restrict__ cv,
                                                float* __restrict__ outT) {
    int lane = threadIdx.x & 63;
    int pix = blockIdx.x * 4 + (threadIdx.x >> 6);   // 12800*4 = 51200 exact
    int b = pix >= HWc;
    int hw = pix - b * HWc;
    int h = hw / Wc;
    int w = hw - h * Wc;
    int c0 = lane * 2;
    int g = lane >> 3;

    const float* cp = cv + (size_t)pix * 96;
    const float* xb = xT + (size_t)b * HWc * Cch;

    float acc0 = 0.f, acc1 = 0.f;
#pragma unroll
    for (int k = 0; k < 9; ++k) {
        float dy = cp[k];
        float dx = cp[9 + k];
        float wt = cp[18 + g * 9 + k];
        float py = (float)(h - 1 + k / 3) + dy;
        float px = (float)(w - 1 + k % 3) + dx;
        float y0f = floorf(py), x0f = floorf(px);
        float fy = py - y0f, fx = px - x0f;
        int y0 = (int)y0f, x0 = (int)x0f;
        int y1 = y0 + 1, x1 = x0 + 1;
        float w00 = (1.f - fy) * (1.f - fx) * wt;
        float w01 = (1.f - fy) * fx * wt;
        float w10 = fy * (1.f - fx) * wt;
        float w11 = fy * fx * wt;

        {
            bool v = (y0 >= 0) & (y0 < Hc) & (x0 >= 0) & (x0 < Wc);
            int yc = min(max(y0, 0), Hc - 1), xc = min(max(x0, 0), Wc - 1);
            float2 t = *reinterpret_cast<const float2*>(&xb[((size_t)yc * Wc + xc) * Cch + c0]);
            float m = v ? w00 : 0.f;
            acc0 = fmaf(m, t.x, acc0);
            acc1 = fmaf(m, t.y, acc1);
        }
        {
            bool v = (y0 >= 0) & (y0 < Hc) & (x1 >= 0) & (x1 < Wc);
            int yc = min(max(y0, 0), Hc - 1), xc = min(max(x1, 0), Wc - 1);
            float2 t = *reinterpret_cast<const float2*>(&xb[((size_t)yc * Wc + xc) * Cch + c0]);
            float m = v ? w01 : 0.f;
            acc0 = fmaf(m, t.x, acc0);
            acc1 = fmaf(m, t.y, acc1);
        }
        {
            bool v = (y1 >= 0) & (y1 < Hc) & (x0 >= 0) & (x0 < Wc);
            int yc = min(max(y1, 0), Hc - 1), xc = min(max(x0, 0), Wc - 1);
            float2 t = *reinterpret_cast<const float2*>(&xb[((size_t)yc * Wc + xc) * Cch + c0]);
            float m = v ? w10 : 0.f;
            acc0 = fmaf(m, t.x, acc0);
            acc1 = fmaf(m, t.y, acc1);
        }
        {
            bool v = (y1 >= 0) & (y1 < Hc) & (x1 >= 0) & (x1 < Wc);
            int yc = min(max(y1, 0), Hc - 1), xc = min(max(x1, 0), Wc - 1);
            float2 t = *reinterpret_cast<const float2*>(&xb[((size_t)yc * Wc + xc) * Cch + c0]);
            float m = v ? w11 : 0.f;
            acc0 = fmaf(m, t.x, acc0);
            acc1 = fmaf(m, t.y, acc1);
        }
    }
    *reinterpret_cast<float2*>(&outT[(size_t)pix * Cch + c0]) = make_float2(acc0, acc1);
}

// ---------------------------------------------------------------------------
// Generic 32x32 tiled transpose (per batch): in [R][Cn] -> out [Cn][R].
// ---------------------------------------------------------------------------
__global__ void transpose_k(const float* __restrict__ in, float* __restrict__ out,
                            int R, int Cn) {
    __shared__ float tile[32][33];
    int b = blockIdx.z;
    const float* inb = in + (size_t)b * R * Cn;
    float* outb = out + (size_t)b * R * Cn;
    int j0 = blockIdx.x * 32;
    int i0 = blockIdx.y * 32;
    for (int di = threadIdx.y; di < 32; di += 8) {
        int i = i0 + di, j = j0 + threadIdx.x;
        if (i < R && j < Cn) tile[di][threadIdx.x] = inb[(size_t)i * Cn + j];
    }
    __syncthreads();
    for (int dj = threadIdx.y; dj < 32; dj += 8) {
        int j = j0 + dj, i = i0 + threadIdx.x;
        if (j < Cn && i < R) outb[(size_t)j * R + i] = tile[threadIdx.x][dj];
    }
}

// ---------------------------------------------------------------------------
// Launch
// ---------------------------------------------------------------------------
extern "C" void kernel_launch(void* const* d_in, const int* in_sizes, int n_in,
                              void* d_out, int out_size, void* d_ws, size_t ws_size,
                              hipStream_t stream) {
    const float* x      = (const float*)d_in[0];
    const float* w_hoff = (const float*)d_in[1];
    const float* b_hoff = (const float*)d_in[2];
    const float* w_hw   = (const float*)d_in[3];
    const float* b_hw   = (const float*)d_in[4];
    const float* w_voff = (const float*)d_in[5];
    const float* b_voff = (const float*)d_in[6];
    const float* w_vw   = (const float*)d_in[7];
    const float* b_vw   = (const float*)d_in[8];
    float* out = (float*)d_out;
    char* ws = (char*)d_ws;

    // Workspace (bytes), all 16B-aligned; total ~88 MB.
    short* whi  = (short*)(ws + 0);              // 147456 B
    short* wlo  = (short*)(ws + 147456);         // 147456 B
    float* bias = (float*)(ws + 294912);         // 768 B
    float* xT   = (float*)(ws + 295680);         // 26,214,400 B (NHWC fp32)
    short* xh   = (short*)(ws + 26510080);       // 13,107,200 B (NHWC bf16 hi)
    short* xl   = (short*)(ws + 39617280);       // 13,107,200 B (NHWC bf16 lo)
    float* convH = (float*)(ws + 52724480);      // 19,660,800 B ([px][96])
    float* convV = (float*)(ws + 72385280);      // 19,660,800 B
    // Aliases (dead buffers reused):
    float* outh = (float*)xh;                    // 26.2 MB over xh+xl (dead after conv)
    float* outv = xT;                            // xT dead after deform pass 1

    hipLaunchKernelGGL(wprep2_k, dim3(288), dim3(256), 0, stream,
                       w_hoff, w_hw, w_voff, w_vw, b_hoff, b_hw, b_voff, b_vw,
                       whi, wlo, bias);

    hipLaunchKernelGGL(pack_k, dim3(800, 4, 2), dim3(32, 8), 0, stream,
                       x, xT, xh, xl);

    hipLaunchKernelGGL(conv_mfma_k, dim3(800, 2), dim3(256), 0, stream,
                       xh, xl, whi, wlo, bias, convH, convV);

    hipLaunchKernelGGL(deform_k, dim3(12800), dim3(256), 0, stream,
                       xT, convH, outh);
    hipLaunchKernelGGL(deform_k, dim3(12800), dim3(256), 0, stream,
                       outh, convV, outv);

    hipLaunchKernelGGL(transpose_k, dim3(4, 800, 2), dim3(32, 8), 0, stream,
                       outv, out, 25600, 128);
}

// Round 5
// 262.125 us; speedup vs baseline: 1.7055x; 1.4955x over previous
//
#include <hip/hip_runtime.h>
#include <hip/hip_bf16.h>
#include <cmath>

// Problem constants: B=2, C=128, H=W=160, K=3, K2=9, G=8, Cg=16.
constexpr int Cch = 128;
constexpr int Hc = 160;
constexpr int Wc = 160;
constexpr int HWc = Hc * Wc;          // 25600
constexpr int NPIX = 2 * HWc;         // 51200

typedef __attribute__((ext_vector_type(8))) short bf16x8;   // 8 bf16 = 4 VGPRs
typedef __attribute__((ext_vector_type(4))) float f32x4;

static __device__ __forceinline__ short f2bf(float v) {
    __hip_bfloat16 h = __float2bfloat16(v);
    return *reinterpret_cast<short*>(&h);
}
static __device__ __forceinline__ float bf2f(short s) {
    __hip_bfloat16 h = *reinterpret_cast<__hip_bfloat16*>(&s);
    return __bfloat162float(h);
}

// ---------------------------------------------------------------------------
// Weight prep. Layout tuned for LDS staging + conflict-free ds_read_b128:
//   whi[((dir*3+third)*48 + kb)*256 + oc*8 + j]   (shorts), same for wlo.
// kb = tap*16 + ks*4 + kgrp encodes the k-block; oc in [0,32) within third;
// weight element = w[ocg = third*32+oc][c = ks*32 + kgrp*8 + j][tap].
// bias[dir*96 + oc] separate.
// ---------------------------------------------------------------------------
__global__ void wprep2_k(const float* __restrict__ wh_off, const float* __restrict__ wh_dyn,
                         const float* __restrict__ wv_off, const float* __restrict__ wv_dyn,
                         const float* __restrict__ bh_off, const float* __restrict__ bh_dyn,
                         const float* __restrict__ bv_off, const float* __restrict__ bv_dyn,
                         short* __restrict__ whi, short* __restrict__ wlo,
                         float* __restrict__ bias) {
    int idx = blockIdx.x * 256 + threadIdx.x;      // 73728 = 2*3*48*32*8 exact
    int j = idx & 7;
    int oc = (idx >> 3) & 31;
    int t = idx >> 8;            // 0..287
    int kb = t % 48;
    int grp = t / 48;            // dir*3+third
    int third = grp % 3, dir = grp / 3;
    int tap = kb >> 4, ks = (kb >> 2) & 3, kgrp = kb & 3;
    int ocg = third * 32 + oc;
    int c = ks * 32 + kgrp * 8 + j;
    const float* woff = dir ? wv_off : wh_off;
    const float* wdyn = dir ? wv_dyn : wh_dyn;
    float v = 0.f;
    if (ocg < 18) v = woff[(ocg * Cch + c) * 3 + tap];
    else if (ocg < 90) v = wdyn[((ocg - 18) * Cch + c) * 3 + tap];
    short hi = f2bf(v);
    whi[idx] = hi;
    wlo[idx] = f2bf(v - bf2f(hi));
    if (idx < 192) {
        int d2 = idx / 96, jb = idx % 96;
        const float* boff = d2 ? bv_off : bh_off;
        const float* bdyn = d2 ? bv_dyn : bh_dyn;
        bias[idx] = jb < 18 ? boff[jb] : (jb < 90 ? bdyn[jb - 18] : 0.f);
    }
}

// ---------------------------------------------------------------------------
// x NCHW -> NHWC, emitting fp32 (deform gather) + bf16 hi + bf16 lo (MFMA).
// ---------------------------------------------------------------------------
__global__ void pack_k(const float* __restrict__ x, float* __restrict__ xT,
                       short* __restrict__ xh, short* __restrict__ xl) {
    __shared__ float tile[32][33];
    int b = blockIdx.z;
    int j0 = blockIdx.x * 32;          // hw
    int i0 = blockIdx.y * 32;          // c
    const float* inb = x + (size_t)b * Cch * HWc;
    for (int di = threadIdx.y; di < 32; di += 8)
        tile[di][threadIdx.x] = inb[(size_t)(i0 + di) * HWc + j0 + threadIdx.x];
    __syncthreads();
    size_t obase = (size_t)b * HWc * Cch;
    for (int dj = threadIdx.y; dj < 32; dj += 8) {
        int hw = j0 + dj, c = i0 + threadIdx.x;
        float v = tile[threadIdx.x][dj];
        size_t o = obase + (size_t)hw * Cch + c;
        xT[o] = v;
        short hi = f2bf(v);
        xh[o] = hi;
        xl[o] = f2bf(v - bf2f(hi));
    }
}

// ---------------------------------------------------------------------------
// MFMA conv with LDS-staged weights. grid=(6, 400): x = dir*3+third,
// y = 128-px tile (consecutive x-blocks share A rows -> L2/L3 reuse).
// Block = 4 waves; wave computes 32 px (2 M-frags) x 32 oc (2 N-frags).
// 3-chain bf16 split: (xh,wh)+(xl,wh)+(xh,wl). B from LDS: layout
// sh[(kb*32+oc)*8], conflict-free for ds_read_b128 (8 accesses/bank).
// Output pixel-major conv[px][96]: 0..8 dy, 9..17 dx, 18..89 dynw.
// ---------------------------------------------------------------------------
__global__ __launch_bounds__(256) void conv_mfma_k(
        const short* __restrict__ xh, const short* __restrict__ xl,
        const short* __restrict__ whi, const short* __restrict__ wlo,
        const float* __restrict__ bias,
        float* __restrict__ convH, float* __restrict__ convV) {
    __shared__ short sh_h[12288];    // 24 KB
    __shared__ short sh_l[12288];    // 24 KB
    int grpi = blockIdx.x;           // dir*3+third
    int dir = grpi / 3, third = grpi - dir * 3;
    int tid = threadIdx.x;
    int lane = tid & 63;
    int wid = tid >> 6;
    int l15 = lane & 15;
    int kgrp = lane >> 4;

    // Stage this group's weights (24KB hi + 24KB lo), linear copy.
    {
        const bf16x8* srcH = reinterpret_cast<const bf16x8*>(whi + (size_t)grpi * 12288);
        const bf16x8* srcL = reinterpret_cast<const bf16x8*>(wlo + (size_t)grpi * 12288);
        bf16x8* dstH = reinterpret_cast<bf16x8*>(sh_h);
        bf16x8* dstL = reinterpret_cast<bf16x8*>(sh_l);
#pragma unroll
        for (int i = 0; i < 6; ++i) {
            dstH[tid + i * 256] = srcH[tid + i * 256];
            dstL[tid + i * 256] = srcL[tid + i * 256];
        }
    }
    __syncthreads();

    int px0 = blockIdx.y * 128 + wid * 32;

    // Per-M-frag pixel coords (lane row = l15)
    int pxA = px0 + l15;
    int pxB = px0 + 16 + l15;
    int bA = pxA >= HWc, bB = pxB >= HWc;
    int hwA = pxA - bA * HWc, hwB = pxB - bB * HWc;
    int hA = hwA / Wc, wA = hwA - hA * Wc;
    int hB = hwB / Wc, wB = hwB - hB * Wc;

    f32x4 acc[2][2];
#pragma unroll
    for (int m = 0; m < 2; ++m)
#pragma unroll
        for (int n = 0; n < 2; ++n) acc[m][n] = f32x4{0.f, 0.f, 0.f, 0.f};

#pragma unroll
    for (int tap = 0; tap < 3; ++tap) {
        int d = tap - 1;
        int vcA, vcB, shwA, shwB;
        if (dir == 0) { vcA = wA + d; shwA = hwA + d; vcB = wB + d; shwB = hwB + d; }
        else          { vcA = hA + d; shwA = hwA + d * Wc; vcB = hB + d; shwB = hwB + d * Wc; }
        bool valA = (unsigned)vcA < 160u;
        bool valB = (unsigned)vcB < 160u;
        int rA = bA * HWc + min(max(shwA, 0), HWc - 1);
        int rB = bB * HWc + min(max(shwB, 0), HWc - 1);
        const short* apA_h = xh + (size_t)rA * Cch + kgrp * 8;
        const short* apA_l = xl + (size_t)rA * Cch + kgrp * 8;
        const short* apB_h = xh + (size_t)rB * Cch + kgrp * 8;
        const short* apB_l = xl + (size_t)rB * Cch + kgrp * 8;
#pragma unroll
        for (int ks = 0; ks < 4; ++ks) {
            bf16x8 ah0 = *reinterpret_cast<const bf16x8*>(apA_h + ks * 32);
            bf16x8 al0 = *reinterpret_cast<const bf16x8*>(apA_l + ks * 32);
            bf16x8 ah1 = *reinterpret_cast<const bf16x8*>(apB_h + ks * 32);
            bf16x8 al1 = *reinterpret_cast<const bf16x8*>(apB_l + ks * 32);
            if (!valA) { ah0 = bf16x8{}; al0 = bf16x8{}; }
            if (!valB) { ah1 = bf16x8{}; al1 = bf16x8{}; }
            int kb = tap * 16 + ks * 4 + kgrp;
            const short* bp = &sh_h[(kb * 32 + l15) * 8];
            const short* bq = &sh_l[(kb * 32 + l15) * 8];
            bf16x8 bh0 = *reinterpret_cast<const bf16x8*>(bp);
            bf16x8 bh1 = *reinterpret_cast<const bf16x8*>(bp + 128);
            bf16x8 bl0 = *reinterpret_cast<const bf16x8*>(bq);
            bf16x8 bl1 = *reinterpret_cast<const bf16x8*>(bq + 128);
            acc[0][0] = __builtin_amdgcn_mfma_f32_16x16x32_bf16(ah0, bh0, acc[0][0], 0, 0, 0);
            acc[0][1] = __builtin_amdgcn_mfma_f32_16x16x32_bf16(ah0, bh1, acc[0][1], 0, 0, 0);
            acc[1][0] = __builtin_amdgcn_mfma_f32_16x16x32_bf16(ah1, bh0, acc[1][0], 0, 0, 0);
            acc[1][1] = __builtin_amdgcn_mfma_f32_16x16x32_bf16(ah1, bh1, acc[1][1], 0, 0, 0);
            acc[0][0] = __builtin_amdgcn_mfma_f32_16x16x32_bf16(al0, bh0, acc[0][0], 0, 0, 0);
            acc[0][1] = __builtin_amdgcn_mfma_f32_16x16x32_bf16(al0, bh1, acc[0][1], 0, 0, 0);
            acc[1][0] = __builtin_amdgcn_mfma_f32_16x16x32_bf16(al1, bh0, acc[1][0], 0, 0, 0);
            acc[1][1] = __builtin_amdgcn_mfma_f32_16x16x32_bf16(al1, bh1, acc[1][1], 0, 0, 0);
            acc[0][0] = __builtin_amdgcn_mfma_f32_16x16x32_bf16(ah0, bl0, acc[0][0], 0, 0, 0);
            acc[0][1] = __builtin_amdgcn_mfma_f32_16x16x32_bf16(ah0, bl1, acc[0][1], 0, 0, 0);
            acc[1][0] = __builtin_amdgcn_mfma_f32_16x16x32_bf16(ah1, bl0, acc[1][0], 0, 0, 0);
            acc[1][1] = __builtin_amdgcn_mfma_f32_16x16x32_bf16(ah1, bl1, acc[1][1], 0, 0, 0);
        }
    }

    // Epilogue: D row = m*16 + kgrp*4 + r (local px), col = third*32 + n*16 + l15.
    float* outp = dir ? convV : convH;
#pragma unroll
    for (int n = 0; n < 2; ++n) {
        int col = third * 32 + n * 16 + l15;
        float bv = bias[dir * 96 + col];
#pragma unroll
        for (int m = 0; m < 2; ++m) {
#pragma unroll
            for (int r = 0; r < 4; ++r) {
                int prow = px0 + m * 16 + kgrp * 4 + r;
                outp[(size_t)prow * 96 + col] = acc[m][n][r] + bv;
            }
        }
    }
}

// ---------------------------------------------------------------------------
// Deformable aggregation. 2 pixels per wave: half-wave (32 lanes) per pixel,
// lane holds 4 channels (float4 gather = 1KB/wave/tap). Gather src NHWC fp32.
// cv = pixel-major conv output [px][96]: dy=cv[k], dx=cv[9+k], wt=cv[18+g*9+k].
// ---------------------------------------------------------------------------
__global__ __launch_bounds__(256) void deform_k(const float* __restrict__ xT,
                                                const float* __restrict__ cv,
                                                float* __restrict__ outT) {
    int tid = threadIdx.x;
    int lane = tid & 63;
    int half = lane >> 5;
    int cl = (lane & 31) * 4;
    int pix = blockIdx.x * 8 + (tid >> 6) * 2 + half;   // 6400*8 = 51200 exact
    int b = pix >= HWc;
    int hw = pix - b * HWc;
    int h = hw / Wc;
    int w = hw - h * Wc;
    int g = (lane & 31) >> 2;

    const float* cp = cv + (size_t)pix * 96;
    const float* xb = xT + (size_t)b * HWc * Cch;

    float4 acc = make_float4(0.f, 0.f, 0.f, 0.f);
#pragma unroll
    for (int k = 0; k < 9; ++k) {
        float dy = cp[k];
        float dx = cp[9 + k];
        float wt = cp[18 + g * 9 + k];
        float py = (float)(h - 1 + k / 3) + dy;
        float px = (float)(w - 1 + k % 3) + dx;
        float y0f = floorf(py), x0f = floorf(px);
        float fy = py - y0f, fx = px - x0f;
        int y0 = (int)y0f, x0 = (int)x0f;
        int y1 = y0 + 1, x1 = x0 + 1;
        float w00 = (1.f - fy) * (1.f - fx) * wt;
        float w01 = (1.f - fy) * fx * wt;
        float w10 = fy * (1.f - fx) * wt;
        float w11 = fy * fx * wt;

        {
            bool v = (y0 >= 0) & (y0 < Hc) & (x0 >= 0) & (x0 < Wc);
            int yc = min(max(y0, 0), Hc - 1), xc = min(max(x0, 0), Wc - 1);
            float4 t = *reinterpret_cast<const float4*>(&xb[((size_t)yc * Wc + xc) * Cch + cl]);
            float m = v ? w00 : 0.f;
            acc.x = fmaf(m, t.x, acc.x); acc.y = fmaf(m, t.y, acc.y);
            acc.z = fmaf(m, t.z, acc.z); acc.w = fmaf(m, t.w, acc.w);
        }
        {
            bool v = (y0 >= 0) & (y0 < Hc) & (x1 >= 0) & (x1 < Wc);
            int yc = min(max(y0, 0), Hc - 1), xc = min(max(x1, 0), Wc - 1);
            float4 t = *reinterpret_cast<const float4*>(&xb[((size_t)yc * Wc + xc) * Cch + cl]);
            float m = v ? w01 : 0.f;
            acc.x = fmaf(m, t.x, acc.x); acc.y = fmaf(m, t.y, acc.y);
            acc.z = fmaf(m, t.z, acc.z); acc.w = fmaf(m, t.w, acc.w);
        }
        {
            bool v = (y1 >= 0) & (y1 < Hc) & (x0 >= 0) & (x0 < Wc);
            int yc = min(max(y1, 0), Hc - 1), xc = min(max(x0, 0), Wc - 1);
            float4 t = *reinterpret_cast<const float4*>(&xb[((size_t)yc * Wc + xc) * Cch + cl]);
            float m = v ? w10 : 0.f;
            acc.x = fmaf(m, t.x, acc.x); acc.y = fmaf(m, t.y, acc.y);
            acc.z = fmaf(m, t.z, acc.z); acc.w = fmaf(m, t.w, acc.w);
        }
        {
            bool v = (y1 >= 0) & (y1 < Hc) & (x1 >= 0) & (x1 < Wc);
            int yc = min(max(y1, 0), Hc - 1), xc = min(max(x1, 0), Wc - 1);
            float4 t = *reinterpret_cast<const float4*>(&xb[((size_t)yc * Wc + xc) * Cch + cl]);
            float m = v ? w11 : 0.f;
            acc.x = fmaf(m, t.x, acc.x); acc.y = fmaf(m, t.y, acc.y);
            acc.z = fmaf(m, t.z, acc.z); acc.w = fmaf(m, t.w, acc.w);
        }
    }
    *reinterpret_cast<float4*>(&outT[(size_t)pix * Cch + cl]) = acc;
}

// ---------------------------------------------------------------------------
// Generic 32x32 tiled transpose (per batch): in [R][Cn] -> out [Cn][R].
// ---------------------------------------------------------------------------
__global__ void transpose_k(const float* __restrict__ in, float* __restrict__ out,
                            int R, int Cn) {
    __shared__ float tile[32][33];
    int b = blockIdx.z;
    const float* inb = in + (size_t)b * R * Cn;
    float* outb = out + (size_t)b * R * Cn;
    int j0 = blockIdx.x * 32;
    int i0 = blockIdx.y * 32;
    for (int di = threadIdx.y; di < 32; di += 8) {
        int i = i0 + di, j = j0 + threadIdx.x;
        if (i < R && j < Cn) tile[di][threadIdx.x] = inb[(size_t)i * Cn + j];
    }
    __syncthreads();
    for (int dj = threadIdx.y; dj < 32; dj += 8) {
        int j = j0 + dj, i = i0 + threadIdx.x;
        if (j < Cn && i < R) outb[(size_t)j * R + i] = tile[threadIdx.x][dj];
    }
}

// ---------------------------------------------------------------------------
// Launch
// ---------------------------------------------------------------------------
extern "C" void kernel_launch(void* const* d_in, const int* in_sizes, int n_in,
                              void* d_out, int out_size, void* d_ws, size_t ws_size,
                              hipStream_t stream) {
    const float* x      = (const float*)d_in[0];
    const float* w_hoff = (const float*)d_in[1];
    const float* b_hoff = (const float*)d_in[2];
    const float* w_hw   = (const float*)d_in[3];
    const float* b_hw   = (const float*)d_in[4];
    const float* w_voff = (const float*)d_in[5];
    const float* b_voff = (const float*)d_in[6];
    const float* w_vw   = (const float*)d_in[7];
    const float* b_vw   = (const float*)d_in[8];
    float* out = (float*)d_out;
    char* ws = (char*)d_ws;

    // Workspace (bytes), all 16B-aligned; total ~88 MB.
    short* whi  = (short*)(ws + 0);              // 147456 B
    short* wlo  = (short*)(ws + 147456);         // 147456 B
    float* bias = (float*)(ws + 294912);         // 768 B
    float* xT   = (float*)(ws + 295680);         // 26,214,400 B (NHWC fp32)
    short* xh   = (short*)(ws + 26510080);       // 13,107,200 B (NHWC bf16 hi)
    short* xl   = (short*)(ws + 39617280);       // 13,107,200 B (NHWC bf16 lo)
    float* convH = (float*)(ws + 52724480);      // 19,660,800 B ([px][96])
    float* convV = (float*)(ws + 72385280);      // 19,660,800 B
    // Aliases (dead buffers reused):
    float* outh = (float*)xh;                    // 26.2 MB over xh+xl (dead after conv)
    float* outv = xT;                            // xT dead after deform pass 1

    hipLaunchKernelGGL(wprep2_k, dim3(288), dim3(256), 0, stream,
                       w_hoff, w_hw, w_voff, w_vw, b_hoff, b_hw, b_voff, b_vw,
                       whi, wlo, bias);

    hipLaunchKernelGGL(pack_k, dim3(800, 4, 2), dim3(32, 8), 0, stream,
                       x, xT, xh, xl);

    hipLaunchKernelGGL(conv_mfma_k, dim3(6, 400), dim3(256), 0, stream,
                       xh, xl, whi, wlo, bias, convH, convV);

    hipLaunchKernelGGL(deform_k, dim3(6400), dim3(256), 0, stream,
                       xT, convH, outh);
    hipLaunchKernelGGL(deform_k, dim3(6400), dim3(256), 0, stream,
                       outh, convV, outv);

    hipLaunchKernelGGL(transpose_k, dim3(4, 800, 2), dim3(32, 8), 0, stream,
                       outv, out, 25600, 128);
}

// Round 10
// 242.657 us; speedup vs baseline: 1.8423x; 1.0802x over previous
//
#include <hip/hip_runtime.h>
#include <hip/hip_bf16.h>
#include <cmath>

// Problem constants: B=2, C=128, H=W=160, K=3, K2=9, G=8, Cg=16.
constexpr int Cch = 128;
constexpr int Hc = 160;
constexpr int Wc = 160;
constexpr int HWc = Hc * Wc;          // 25600
constexpr int NPIX = 2 * HWc;         // 51200

typedef __attribute__((ext_vector_type(8))) short bf16x8;   // 8 bf16 = 4 VGPRs
typedef __attribute__((ext_vector_type(4))) float f32x4;

static __device__ __forceinline__ short f2bf(float v) {
    __hip_bfloat16 h = __float2bfloat16(v);
    return *reinterpret_cast<short*>(&h);
}
static __device__ __forceinline__ float bf2f(short s) {
    __hip_bfloat16 h = *reinterpret_cast<__hip_bfloat16*>(&s);
    return __bfloat162float(h);
}

// ---------------------------------------------------------------------------
// Weight prep. Layout tuned for LDS staging + conflict-free ds_read_b128:
//   whi[((dir*3+third)*48 + kb)*256 + oc*8 + j]   (shorts), same for wlo.
// kb = tap*16 + ks*4 + kgrp; oc in [0,32) within third;
// element = w[ocg = third*32+oc][c = ks*32 + kgrp*8 + j][tap].
// ---------------------------------------------------------------------------
__global__ void wprep2_k(const float* __restrict__ wh_off, const float* __restrict__ wh_dyn,
                         const float* __restrict__ wv_off, const float* __restrict__ wv_dyn,
                         const float* __restrict__ bh_off, const float* __restrict__ bh_dyn,
                         const float* __restrict__ bv_off, const float* __restrict__ bv_dyn,
                         short* __restrict__ whi, short* __restrict__ wlo,
                         float* __restrict__ bias) {
    int idx = blockIdx.x * 256 + threadIdx.x;      // 73728 = 2*3*48*32*8 exact
    int j = idx & 7;
    int oc = (idx >> 3) & 31;
    int t = idx >> 8;            // 0..287
    int kb = t % 48;
    int grp = t / 48;            // dir*3+third
    int third = grp % 3, dir = grp / 3;
    int tap = kb >> 4, ks = (kb >> 2) & 3, kgrp = kb & 3;
    int ocg = third * 32 + oc;
    int c = ks * 32 + kgrp * 8 + j;
    const float* woff = dir ? wv_off : wh_off;
    const float* wdyn = dir ? wv_dyn : wh_dyn;
    float v = 0.f;
    if (ocg < 18) v = woff[(ocg * Cch + c) * 3 + tap];
    else if (ocg < 90) v = wdyn[((ocg - 18) * Cch + c) * 3 + tap];
    short hi = f2bf(v);
    whi[idx] = hi;
    wlo[idx] = f2bf(v - bf2f(hi));
    if (idx < 192) {
        int d2 = idx / 96, jb = idx % 96;
        const float* boff = d2 ? bv_off : bh_off;
        const float* bdyn = d2 ? bv_dyn : bh_dyn;
        bias[idx] = jb < 18 ? boff[jb] : (jb < 90 ? bdyn[jb - 18] : 0.f);
    }
}

// ---------------------------------------------------------------------------
// x NCHW -> NHWC, emitting fp32 (deform gather) + bf16 hi + bf16 lo (MFMA).
// ---------------------------------------------------------------------------
__global__ void pack_k(const float* __restrict__ x, float* __restrict__ xT,
                       short* __restrict__ xh, short* __restrict__ xl) {
    __shared__ float tile[32][33];
    int b = blockIdx.z;
    int j0 = blockIdx.x * 32;          // hw
    int i0 = blockIdx.y * 32;          // c
    const float* inb = x + (size_t)b * Cch * HWc;
    for (int di = threadIdx.y; di < 32; di += 8)
        tile[di][threadIdx.x] = inb[(size_t)(i0 + di) * HWc + j0 + threadIdx.x];
    __syncthreads();
    size_t obase = (size_t)b * HWc * Cch;
    for (int dj = threadIdx.y; dj < 32; dj += 8) {
        int hw = j0 + dj, c = i0 + threadIdx.x;
        float v = tile[threadIdx.x][dj];
        size_t o = obase + (size_t)hw * Cch + c;
        xT[o] = v;
        short hi = f2bf(v);
        xh[o] = hi;
        xl[o] = f2bf(v - bf2f(hi));
    }
}

// ---------------------------------------------------------------------------
// MFMA conv with LDS-staged weights + XCD-aware swizzle.
// Flat grid 1200. work = (bid%8)*150 + bid/8  -> each XCD owns a contiguous
// stripe of work; work = ytile*6 + group so one ytile's 6 (dir,third) groups
// run temporally adjacent ON THE SAME XCD -> x-stripe and all 6 weight sets
// (288 KB) stay L2-resident (kills the 182 MB redundant fetch of R5).
// Block = 4 waves; wave computes 64 px (4 M-frags) x 32 oc (2 N-frags):
// 48 ds_read_b128 feed 288 MFMAs -> MFMA-bound.
// 3-chain bf16 split: (xh,wh)+(xl,wh)+(xh,wl).
// Output pixel-major conv[px][96]: 0..8 dy, 9..17 dx, 18..89 dynw.
// ---------------------------------------------------------------------------
__global__ __launch_bounds__(256) void conv_mfma_k(
        const short* __restrict__ xh, const short* __restrict__ xl,
        const short* __restrict__ whi, const short* __restrict__ wlo,
        const float* __restrict__ bias,
        float* __restrict__ convH, float* __restrict__ convV) {
    __shared__ short sh_h[12288];    // 24 KB
    __shared__ short sh_l[12288];    // 24 KB
    int work = (blockIdx.x & 7) * 150 + (blockIdx.x >> 3);   // bijective, 1200=8*150
    int ytile = work / 6;            // 0..199
    int grpi = work - ytile * 6;     // dir*3+third
    int dir = grpi / 3, third = grpi - dir * 3;
    int tid = threadIdx.x;
    int lane = tid & 63;
    int wid = tid >> 6;
    int l15 = lane & 15;
    int kgrp = lane >> 4;

    // Stage this group's weights (24KB hi + 24KB lo), linear copy.
    {
        const bf16x8* srcH = reinterpret_cast<const bf16x8*>(whi + (size_t)grpi * 12288);
        const bf16x8* srcL = reinterpret_cast<const bf16x8*>(wlo + (size_t)grpi * 12288);
        bf16x8* dstH = reinterpret_cast<bf16x8*>(sh_h);
        bf16x8* dstL = reinterpret_cast<bf16x8*>(sh_l);
#pragma unroll
        for (int i = 0; i < 6; ++i) {
            dstH[tid + i * 256] = srcH[tid + i * 256];
            dstL[tid + i * 256] = srcL[tid + i * 256];
        }
    }
    __syncthreads();

    int px0 = ytile * 256 + wid * 64;

    // Per-M-frag pixel coords (lane row = l15)
    int bm[4], hwm[4], hm[4], wm[4];
#pragma unroll
    for (int m = 0; m < 4; ++m) {
        int px = px0 + m * 16 + l15;
        int bb = px >= HWc;
        int hw = px - bb * HWc;
        bm[m] = bb; hwm[m] = hw;
        hm[m] = hw / Wc; wm[m] = hw - hm[m] * Wc;
    }

    f32x4 acc[4][2];
#pragma unroll
    for (int m = 0; m < 4; ++m)
#pragma unroll
        for (int n = 0; n < 2; ++n) acc[m][n] = f32x4{0.f, 0.f, 0.f, 0.f};

#pragma unroll
    for (int tap = 0; tap < 3; ++tap) {
        int d = tap - 1;
        const short* aph[4];
        const short* apl[4];
        bool val[4];
#pragma unroll
        for (int m = 0; m < 4; ++m) {
            int vc = (dir == 0) ? (wm[m] + d) : (hm[m] + d);
            int shw = hwm[m] + ((dir == 0) ? d : d * Wc);
            val[m] = (unsigned)vc < 160u;
            int r = bm[m] * HWc + min(max(shw, 0), HWc - 1);
            aph[m] = xh + (size_t)r * Cch + kgrp * 8;
            apl[m] = xl + (size_t)r * Cch + kgrp * 8;
        }
#pragma unroll
        for (int ks = 0; ks < 4; ++ks) {
            bf16x8 ah[4], al[4];
#pragma unroll
            for (int m = 0; m < 4; ++m) {
                ah[m] = *reinterpret_cast<const bf16x8*>(aph[m] + ks * 32);
                al[m] = *reinterpret_cast<const bf16x8*>(apl[m] + ks * 32);
                if (!val[m]) { ah[m] = bf16x8{}; al[m] = bf16x8{}; }
            }
            int kb = tap * 16 + ks * 4 + kgrp;
            const short* bp = &sh_h[(kb * 32 + l15) * 8];
            const short* bq = &sh_l[(kb * 32 + l15) * 8];
            bf16x8 bh0 = *reinterpret_cast<const bf16x8*>(bp);
            bf16x8 bh1 = *reinterpret_cast<const bf16x8*>(bp + 128);
            bf16x8 bl0 = *reinterpret_cast<const bf16x8*>(bq);
            bf16x8 bl1 = *reinterpret_cast<const bf16x8*>(bq + 128);
#pragma unroll
            for (int m = 0; m < 4; ++m) {
                acc[m][0] = __builtin_amdgcn_mfma_f32_16x16x32_bf16(ah[m], bh0, acc[m][0], 0, 0, 0);
                acc[m][1] = __builtin_amdgcn_mfma_f32_16x16x32_bf16(ah[m], bh1, acc[m][1], 0, 0, 0);
            }
#pragma unroll
            for (int m = 0; m < 4; ++m) {
                acc[m][0] = __builtin_amdgcn_mfma_f32_16x16x32_bf16(al[m], bh0, acc[m][0], 0, 0, 0);
                acc[m][1] = __builtin_amdgcn_mfma_f32_16x16x32_bf16(al[m], bh1, acc[m][1], 0, 0, 0);
            }
#pragma unroll
            for (int m = 0; m < 4; ++m) {
                acc[m][0] = __builtin_amdgcn_mfma_f32_16x16x32_bf16(ah[m], bl0, acc[m][0], 0, 0, 0);
                acc[m][1] = __builtin_amdgcn_mfma_f32_16x16x32_bf16(ah[m], bl1, acc[m][1], 0, 0, 0);
            }
        }
    }

    // Epilogue: D row = m*16 + kgrp*4 + r (local px), col = third*32 + n*16 + l15.
    float* outp = dir ? convV : convH;
#pragma unroll
    for (int n = 0; n < 2; ++n) {
        int col = third * 32 + n * 16 + l15;
        float bv = bias[dir * 96 + col];
#pragma unroll
        for (int m = 0; m < 4; ++m) {
#pragma unroll
            for (int r = 0; r < 4; ++r) {
                int prow = px0 + m * 16 + kgrp * 4 + r;
                outp[(size_t)prow * 96 + col] = acc[m][n][r] + bv;
            }
        }
    }
}

// ---------------------------------------------------------------------------
// Deformable aggregation. 2 pixels per wave: half-wave (32 lanes) per pixel,
// lane holds 4 channels (float4 gather = 1KB/wave/tap). Gather src NHWC fp32.
// XCD-chunked block remap: each XCD owns a contiguous 1/8 of pixels so its
// L2 holds the ~3.3MB slice of the gather source.
// cv = pixel-major conv output [px][96]: dy=cv[k], dx=cv[9+k], wt=cv[18+g*9+k].
// ---------------------------------------------------------------------------
__global__ __launch_bounds__(256) void deform_k(const float* __restrict__ xT,
                                                const float* __restrict__ cv,
                                                float* __restrict__ outT) {
    int tid = threadIdx.x;
    int lane = tid & 63;
    int half = lane >> 5;
    int cl = (lane & 31) * 4;
    int work = (blockIdx.x & 7) * 800 + (blockIdx.x >> 3);   // bijective, 6400=8*800
    int pix = work * 8 + (tid >> 6) * 2 + half;
    int b = pix >= HWc;
    int hw = pix - b * HWc;
    int h = hw / Wc;
    int w = hw - h * Wc;
    int g = (lane & 31) >> 2;

    const float* cp = cv + (size_t)pix * 96;
    const float* xb = xT + (size_t)b * HWc * Cch;

    float4 acc = make_float4(0.f, 0.f, 0.f, 0.f);
#pragma unroll
    for (int k = 0; k < 9; ++k) {
        float dy = cp[k];
        float dx = cp[9 + k];
        float wt = cp[18 + g * 9 + k];
        float py = (float)(h - 1 + k / 3) + dy;
        float px = (float)(w - 1 + k % 3) + dx;
        float y0f = floorf(py), x0f = floorf(px);
        float fy = py - y0f, fx = px - x0f;
        int y0 = (int)y0f, x0 = (int)x0f;
        int y1 = y0 + 1, x1 = x0 + 1;
        float w00 = (1.f - fy) * (1.f - fx) * wt;
        float w01 = (1.f - fy) * fx * wt;
        float w10 = fy * (1.f - fx) * wt;
        float w11 = fy * fx * wt;

        {
            bool v = (y0 >= 0) & (y0 < Hc) & (x0 >= 0) & (x0 < Wc);
            int yc = min(max(y0, 0), Hc - 1), xc = min(max(x0, 0), Wc - 1);
            float4 t = *reinterpret_cast<const float4*>(&xb[((size_t)yc * Wc + xc) * Cch + cl]);
            float m = v ? w00 : 0.f;
            acc.x = fmaf(m, t.x, acc.x); acc.y = fmaf(m, t.y, acc.y);
            acc.z = fmaf(m, t.z, acc.z); acc.w = fmaf(m, t.w, acc.w);
        }
        {
            bool v = (y0 >= 0) & (y0 < Hc) & (x1 >= 0) & (x1 < Wc);
            int yc = min(max(y0, 0), Hc - 1), xc = min(max(x1, 0), Wc - 1);
            float4 t = *reinterpret_cast<const float4*>(&xb[((size_t)yc * Wc + xc) * Cch + cl]);
            float m = v ? w01 : 0.f;
            acc.x = fmaf(m, t.x, acc.x); acc.y = fmaf(m, t.y, acc.y);
            acc.z = fmaf(m, t.z, acc.z); acc.w = fmaf(m, t.w, acc.w);
        }
        {
            bool v = (y1 >= 0) & (y1 < Hc) & (x0 >= 0) & (x0 < Wc);
            int yc = min(max(y1, 0), Hc - 1), xc = min(max(x0, 0), Wc - 1);
            float4 t = *reinterpret_cast<const float4*>(&xb[((size_t)yc * Wc + xc) * Cch + cl]);
            float m = v ? w10 : 0.f;
            acc.x = fmaf(m, t.x, acc.x); acc.y = fmaf(m, t.y, acc.y);
            acc.z = fmaf(m, t.z, acc.z); acc.w = fmaf(m, t.w, acc.w);
        }
        {
            bool v = (y1 >= 0) & (y1 < Hc) & (x1 >= 0) & (x1 < Wc);
            int yc = min(max(y1, 0), Hc - 1), xc = min(max(x1, 0), Wc - 1);
            float4 t = *reinterpret_cast<const float4*>(&xb[((size_t)yc * Wc + xc) * Cch + cl]);
            float m = v ? w11 : 0.f;
            acc.x = fmaf(m, t.x, acc.x); acc.y = fmaf(m, t.y, acc.y);
            acc.z = fmaf(m, t.z, acc.z); acc.w = fmaf(m, t.w, acc.w);
        }
    }
    *reinterpret_cast<float4*>(&outT[(size_t)pix * Cch + cl]) = acc;
}

// ---------------------------------------------------------------------------
// Generic 32x32 tiled transpose (per batch): in [R][Cn] -> out [Cn][R].
// ---------------------------------------------------------------------------
__global__ void transpose_k(const float* __restrict__ in, float* __restrict__ out,
                            int R, int Cn) {
    __shared__ float tile[32][33];
    int b = blockIdx.z;
    const float* inb = in + (size_t)b * R * Cn;
    float* outb = out + (size_t)b * R * Cn;
    int j0 = blockIdx.x * 32;
    int i0 = blockIdx.y * 32;
    for (int di = threadIdx.y; di < 32; di += 8) {
        int i = i0 + di, j = j0 + threadIdx.x;
        if (i < R && j < Cn) tile[di][threadIdx.x] = inb[(size_t)i * Cn + j];
    }
    __syncthreads();
    for (int dj = threadIdx.y; dj < 32; dj += 8) {
        int j = j0 + dj, i = i0 + threadIdx.x;
        if (j < Cn && i < R) outb[(size_t)j * R + i] = tile[threadIdx.x][dj];
    }
}

// ---------------------------------------------------------------------------
// Launch
// ---------------------------------------------------------------------------
extern "C" void kernel_launch(void* const* d_in, const int* in_sizes, int n_in,
                              void* d_out, int out_size, void* d_ws, size_t ws_size,
                              hipStream_t stream) {
    const float* x      = (const float*)d_in[0];
    const float* w_hoff = (const float*)d_in[1];
    const float* b_hoff = (const float*)d_in[2];
    const float* w_hw   = (const float*)d_in[3];
    const float* b_hw   = (const float*)d_in[4];
    const float* w_voff = (const float*)d_in[5];
    const float* b_voff = (const float*)d_in[6];
    const float* w_vw   = (const float*)d_in[7];
    const float* b_vw   = (const float*)d_in[8];
    float* out = (float*)d_out;
    char* ws = (char*)d_ws;

    // Workspace (bytes), all 16B-aligned; total ~88 MB.
    short* whi  = (short*)(ws + 0);              // 147456 B
    short* wlo  = (short*)(ws + 147456);         // 147456 B
    float* bias = (float*)(ws + 294912);         // 768 B
    float* xT   = (float*)(ws + 295680);         // 26,214,400 B (NHWC fp32)
    short* xh   = (short*)(ws + 26510080);       // 13,107,200 B (NHWC bf16 hi)
    short* xl   = (short*)(ws + 39617280);       // 13,107,200 B (NHWC bf16 lo)
    float* convH = (float*)(ws + 52724480);      // 19,660,800 B ([px][96])
    float* convV = (float*)(ws + 72385280);      // 19,660,800 B
    // Aliases (dead buffers reused):
    float* outh = (float*)xh;                    // 26.2 MB over xh+xl (dead after conv)
    float* outv = xT;                            // xT dead after deform pass 1

    hipLaunchKernelGGL(wprep2_k, dim3(288), dim3(256), 0, stream,
                       w_hoff, w_hw, w_voff, w_vw, b_hoff, b_hw, b_voff, b_vw,
                       whi, wlo, bias);

    hipLaunchKernelGGL(pack_k, dim3(800, 4, 2), dim3(32, 8), 0, stream,
                       x, xT, xh, xl);

    hipLaunchKernelGGL(conv_mfma_k, dim3(1200), dim3(256), 0, stream,
                       xh, xl, whi, wlo, bias, convH, convV);

    hipLaunchKernelGGL(deform_k, dim3(6400), dim3(256), 0, stream,
                       xT, convH, outh);
    hipLaunchKernelGGL(deform_k, dim3(6400), dim3(256), 0, stream,
                       outh, convV, outv);

    hipLaunchKernelGGL(transpose_k, dim3(4, 800, 2), dim3(32, 8), 0, stream,
                       outv, out, 25600, 128);
}